// Round 19
// baseline (122.697 us; speedup 1.0000x reference)
//
#include <hip/hip_runtime.h>

#define NREL 8192
#define RD   256
#define RSHIFT 16.0f   // constant softmax shift: >= max(right) with huge margin

typedef float f32x4 __attribute__((ext_vector_type(4)));
typedef short s16x8 __attribute__((ext_vector_type(8)));
typedef unsigned int  u32;
typedef unsigned short u16;
typedef unsigned long long u64;
typedef u32 u32x4 __attribute__((ext_vector_type(4)));

__device__ __forceinline__ u16 f2bf(float f) {
    u32 b = __float_as_uint(f);
    return (u16)((b + 0x7FFFu + ((b >> 16) & 1u)) >> 16);   // RNE
}
__device__ __forceinline__ u32 pk_bf16(float lo, float hi) {
    u32 r;
    asm("v_cvt_pk_bf16_f32 %0, %1, %2" : "=v"(r) : "v"(lo), "v"(hi));
    return r;   // low16 = bf16(lo), high16 = bf16(hi), RNE
}

// ---------------- K1: fused {u_left/u_right} + {Bf fragment repack} ---------
__global__ __launch_bounds__(256) void k_prep_bf(
    const float* __restrict__ W, const float* __restrict__ wl,
    const float* __restrict__ wr, float* __restrict__ ul,
    float* __restrict__ ur, const float* __restrict__ R,
    u32* __restrict__ Bf)
{
    __shared__ float sL[256], sR[256];
    const int t = threadIdx.x;
    if (blockIdx.x < 32) {
        const int d = blockIdx.x * 16 + (t & 15);
        float aL = 0.f, aR = 0.f;
        for (int h = (t >> 4); h < 256; h += 16) {
            float w = W[h * 512 + d];
            aL += w * wl[h];
            aR += w * wr[h];
        }
        sL[t] = aL; sR[t] = aR;
        __syncthreads();
        if (t < 16) {
            float xL = 0.f, xR = 0.f;
            for (int g = 0; g < 16; g++) { xL += sL[g * 16 + t]; xR += sR[g * 16 + t]; }
            ul[blockIdx.x * 16 + t] = xL;
            ur[blockIdx.x * 16 + t] = xR;
        }
        return;
    }
    if (!Bf) return;
    const int b     = blockIdx.x - 32;
    const int jt    = b >> 1;
    const int fbase = (b & 1) * 1024;
    #pragma unroll
    for (int rep = 0; rep < 4; rep++) {
        const int f    = fbase + rep * 256 + t;   // 0..2047
        const int kk   = f >> 10;
        const int cg   = (f >> 6) & 15;
        const int lane = f & 63;
        const int lq   = lane >> 4;
        const int l15  = lane & 15;
        const int j0   = (jt << 6) + kk * 32 + lq * 8;
        const int n    = cg * 16 + l15;
        const float* src = R + (size_t)j0 * RD + n;
        float v[8];
        #pragma unroll
        for (int e = 0; e < 8; e++) v[e] = src[(size_t)e * RD];
        u32x4 w;
        w.x = pk_bf16(v[0], v[1]);
        w.y = pk_bf16(v[2], v[3]);
        w.z = pk_bf16(v[4], v[5]);
        w.w = pk_bf16(v[6], v[7]);
        *(u32x4*)(Bf + ((size_t)jt * 2048 + f) * 4) = w;
    }
}

// ---------------- K2: left/right rows (no atomics) --------------------------
__global__ __launch_bounds__(256) void k_lr(
    const float* __restrict__ ctx, const float* __restrict__ ul,
    const float* __restrict__ ur, const float* __restrict__ bl,
    const float* __restrict__ br, float* __restrict__ left,
    float* __restrict__ right)
{
    const int lane = threadIdx.x & 63;
    const int row  = blockIdx.x * 4 + (threadIdx.x >> 6);
    const f32x4* cv = (const f32x4*)(ctx + (size_t)row * 512);
    const f32x4* uv = (const f32x4*)ul;
    const f32x4* vv = (const f32x4*)ur;
    f32x4 c0 = cv[lane], c1 = cv[lane + 64];
    f32x4 u0 = uv[lane], u1 = uv[lane + 64];
    f32x4 v0 = vv[lane], v1 = vv[lane + 64];
    float dl = c0.x*u0.x + c0.y*u0.y + c0.z*u0.z + c0.w*u0.w
             + c1.x*u1.x + c1.y*u1.y + c1.z*u1.z + c1.w*u1.w;
    float dr = c0.x*v0.x + c0.y*v0.y + c0.z*v0.z + c0.w*v0.w
             + c1.x*v1.x + c1.y*v1.y + c1.z*v1.z + c1.w*v1.w;
    #pragma unroll
    for (int o = 1; o < 64; o <<= 1) { dl += __shfl_xor(dl, o); dr += __shfl_xor(dr, o); }
    if (lane == 0) {
        left[row]  = dl + bl[0];
        right[row] = dr + br[0];
    }
}

// ---------------- K3s: SEQUENTIAL-STREAM fused attention (S=1) --------------
// grid 256 (1 block/CU), 512 thr (8 waves), 32 rows/block, 128 phases x 64 j.
// adj: 32 per-block row-streams read strictly sequentially (256 B/row/phase)
// -> copy-kernel access pattern. Denominators complete in-block -> direct
// out write (no split-K, no k_red, no pnum roundtrip).
__global__ __launch_bounds__(512) void k_attn_seq(
    const float* __restrict__ adj, const s16x8* __restrict__ Bf,
    const float* __restrict__ left, const float* __restrict__ right,
    float* __restrict__ out)
{
    __shared__ u32   Pl[2][1024];   // 2 x (32 rows x 64 j bf16, swizzled) = 8 KB
    __shared__ float dnm[32];

    const int tid  = threadIdx.x;
    const int lane = tid & 63;
    const int wv   = tid >> 6;      // 0..7 -> output cols wv*32
    const int l15  = lane & 15;
    const int lq   = lane >> 4;
    const int rowblk = (int)blockIdx.x * 32;

    const int pr = tid >> 4;        // 0..31 (P-gen row)
    const int pq = tid & 15;        // j = p*64 + pq*4 .. +3

    const float lft = left[rowblk + pr];
    float z = lft + RSHIFT; const float m = fmaxf(z, 0.2f * z);

    f32x4 acc[2][2];
    #pragma unroll
    for (int i = 0; i < 2; i++) { acc[i][0] = (f32x4)0.f; acc[i][1] = (f32x4)0.f; }
    float dp = 0.f;

    const f32x4* adjv = (const f32x4*)adj;
    const f32x4* rv4  = (const f32x4*)right;
    const size_t arow = (size_t)(rowblk + pr) * 2048;   // f32x4 units/row

    const u32 widx = (u32)pr * 32 + (((u32)pq * 2) ^ (((u32)pr & 7) << 2));

    #define BLOAD(DST, T)                                                      \
        _Pragma("unroll")                                                      \
        for (int kk = 0; kk < 2; kk++)                                         \
            _Pragma("unroll")                                                  \
            for (int ct = 0; ct < 2; ct++)                                     \
                DST[kk][ct] = Bf[(size_t)(T) * 2048 + kk * 1024                \
                                 + (wv * 2 + ct) * 64 + lane];

    #define MFMA_PH(BUF, BSLOT)                                                \
        {                                                                      \
            const u16* Pu = (const u16*)Pl[BUF];                               \
            _Pragma("unroll")                                                  \
            for (int kk = 0; kk < 2; kk++) {                                   \
                s16x8 af[2];                                                   \
                _Pragma("unroll")                                              \
                for (int rt = 0; rt < 2; rt++) {                               \
                    const int row = rt * 16 + l15;                             \
                    const int us  = row * 64                                   \
                                  + ((kk * 32 + lq * 8) ^ ((row & 7) << 3));   \
                    af[rt] = *(const s16x8*)(Pu + us);                         \
                }                                                              \
                _Pragma("unroll")                                              \
                for (int ct = 0; ct < 2; ct++)                                 \
                    _Pragma("unroll")                                          \
                    for (int rt = 0; rt < 2; rt++)                             \
                        acc[rt][ct] = __builtin_amdgcn_mfma_f32_16x16x32_bf16( \
                            af[rt], BSLOT[kk][ct], acc[rt][ct], 0, 0, 0);      \
            }                                                                  \
        }

    #define PGEN(BUF, AV, RV)                                                  \
        {                                                                      \
            float pa[4];                                                       \
            _Pragma("unroll")                                                  \
            for (int e = 0; e < 4; e++) {                                      \
                const float r = RV[e];                                         \
                float z0 = lft + r; float s0 = fmaxf(z0, 0.2f * z0);           \
                pa[e] = AV[e] * __expf(s0 - m);                                \
            }                                                                  \
            dp += pa[0] + pa[1] + pa[2] + pa[3];                               \
            Pl[BUF][widx]     = pk_bf16(pa[0], pa[1]);                         \
            Pl[BUF][widx + 1] = pk_bf16(pa[2], pa[3]);                         \
        }

    // ---- prologue: stage phases 0 (slot A), 1 (slot B); B-frags for tile 0
    f32x4 aA = adjv[arow + pq];
    f32x4 rA = rv4[pq];
    f32x4 aB = adjv[arow + 16 + pq];
    f32x4 rB = rv4[16 + pq];
    s16x8 bA[2][2], bB[2][2];
    BLOAD(bA, 0);

    for (int p = 0; p < 128; p += 2) {
        // ===== phase p (slot A, Pl[0]) =====
        PGEN(0, aA, rA);
        asm volatile("s_waitcnt lgkmcnt(0)" ::: "memory");
        __builtin_amdgcn_s_barrier();
        {
            const int p2 = (p + 2 < 128) ? p + 2 : 0;   // 2-deep sequential stage
            aA = adjv[arow + p2 * 16 + pq];
            rA = rv4[p2 * 16 + pq];
        }
        BLOAD(bB, p + 1);
        MFMA_PH(0, bA);

        // ===== phase p+1 (slot B, Pl[1]) =====
        PGEN(1, aB, rB);
        asm volatile("s_waitcnt lgkmcnt(0)" ::: "memory");
        __builtin_amdgcn_s_barrier();
        {
            const int p3 = (p + 3 < 128) ? p + 3 : 0;
            aB = adjv[arow + p3 * 16 + pq];
            rB = rv4[p3 * 16 + pq];
        }
        {
            const int p2 = (p + 2 < 128) ? p + 2 : 0;
            BLOAD(bA, p2);
        }
        MFMA_PH(1, bB);
    }
    #undef BLOAD
    #undef MFMA_PH
    #undef PGEN

    // ---- denominators: reduce over the 16 pq lanes, then LDS
    #pragma unroll
    for (int o = 1; o < 16; o <<= 1) dp += __shfl_xor(dp, o);
    if (pq == 0) dnm[pr] = dp;
    asm volatile("s_waitcnt lgkmcnt(0)" ::: "memory");
    __builtin_amdgcn_s_barrier();

    // ---- epilogue: out = relu(acc / dnm), direct write
    #pragma unroll
    for (int rt = 0; rt < 2; rt++)
        #pragma unroll
        for (int ct = 0; ct < 2; ct++)
            #pragma unroll
            for (int r = 0; r < 4; r++) {
                const int row = rt * 16 + lq * 4 + r;
                float v = acc[rt][ct][r] / dnm[row];
                out[(size_t)(rowblk + row) * RD + (wv * 32 + ct * 16 + l15)] =
                    fmaxf(v, 0.f);
            }
}

// ---------------- legacy fallback (tiny ws): direct adj, no precompute ------
__global__ __launch_bounds__(512) void k_attn_leg(
    const float* __restrict__ adj, const float* __restrict__ rel,
    const float* __restrict__ left, const float* __restrict__ right,
    float* __restrict__ outp)
{
    __shared__ u32   Pl[64 * 32];
    __shared__ float dnm[64];
    const int tid  = threadIdx.x;
    const int lane = tid & 63;
    const int wv   = tid >> 6;
    const int l15  = lane & 15;
    const int lq   = lane >> 4;
    const int rowblk = blockIdx.x * 64;
    const int pr = tid >> 4, pq = tid & 15;
    const float lft0 = left[rowblk + pr];
    const float lft1 = left[rowblk + pr + 32];
    float z;
    z = lft0 + RSHIFT; const float m0 = fmaxf(z, 0.2f * z);
    z = lft1 + RSHIFT; const float m1 = fmaxf(z, 0.2f * z);
    f32x4 acc[4][2];
    #pragma unroll
    for (int i = 0; i < 4; i++) { acc[i][0] = (f32x4)0.f; acc[i][1] = (f32x4)0.f; }
    float dp0 = 0.f, dp1 = 0.f;
    const f32x4* adjv = (const f32x4*)adj;
    const f32x4* rv4  = (const f32x4*)right;
    const size_t arow0 = (size_t)(rowblk + pr) * 2048;
    const size_t arow1 = (size_t)(rowblk + pr + 32) * 2048;
    const int n0 = wv * 32 + l15;
    const u32 widx0 = (u32)pr * 32 + (((u32)pq * 2) ^ (((u32)pr & 7) << 2));
    const u32 widx1 = widx0 + 1024;
    for (int jb = 0; jb < NREL; jb += 64) {
        f32x4 a0 = adjv[arow0 + (jb >> 2) + pq];
        f32x4 a1 = adjv[arow1 + (jb >> 2) + pq];
        f32x4 rv = rv4[(jb >> 2) + pq];
        s16x8 bc[2][2];
        #pragma unroll
        for (int kk = 0; kk < 2; kk++)
            #pragma unroll
            for (int ct = 0; ct < 2; ct++) {
                const float* rp = rel + (size_t)(jb + kk * 32 + lq * 8) * RD
                                      + (n0 + ct * 16);
                s16x8 b;
                #pragma unroll
                for (int e = 0; e < 8; e++) b[e] = (short)f2bf(rp[(size_t)e * RD]);
                bc[kk][ct] = b;
            }
        float pa[4], pb[4];
        #pragma unroll
        for (int e = 0; e < 4; e++) {
            const float r = rv[e];
            float z0 = lft0 + r; float s0 = fmaxf(z0, 0.2f * z0);
            pa[e] = a0[e] * __expf(s0 - m0);
            float z1 = lft1 + r; float s1 = fmaxf(z1, 0.2f * z1);
            pb[e] = a1[e] * __expf(s1 - m1);
        }
        dp0 += pa[0] + pa[1] + pa[2] + pa[3];
        dp1 += pb[0] + pb[1] + pb[2] + pb[3];
        Pl[widx0]     = pk_bf16(pa[0], pa[1]);
        Pl[widx0 + 1] = pk_bf16(pa[2], pa[3]);
        Pl[widx1]     = pk_bf16(pb[0], pb[1]);
        Pl[widx1 + 1] = pk_bf16(pb[2], pb[3]);
        __syncthreads();
        #pragma unroll
        for (int kk = 0; kk < 2; kk++) {
            s16x8 af[4];
            #pragma unroll
            for (int rt = 0; rt < 4; rt++) {
                const int row = rt * 16 + l15;
                const int us  = row * 64 + ((kk * 32 + lq * 8) ^ ((row & 7) << 3));
                af[rt] = *(const s16x8*)((const u16*)Pl + us);
            }
            #pragma unroll
            for (int ct = 0; ct < 2; ct++)
                #pragma unroll
                for (int rt = 0; rt < 4; rt++)
                    acc[rt][ct] = __builtin_amdgcn_mfma_f32_16x16x32_bf16(
                        af[rt], bc[kk][ct], acc[rt][ct], 0, 0, 0);
        }
        __syncthreads();
    }
    #pragma unroll
    for (int o = 1; o < 16; o <<= 1) { dp0 += __shfl_xor(dp0, o); dp1 += __shfl_xor(dp1, o); }
    if (pq == 0) { dnm[pr] = dp0; dnm[pr + 32] = dp1; }
    __syncthreads();
    #pragma unroll
    for (int rt = 0; rt < 4; rt++)
        #pragma unroll
        for (int ct = 0; ct < 2; ct++)
            #pragma unroll
            for (int r = 0; r < 4; r++) {
                const int row = rt * 16 + lq * 4 + r;
                float v = acc[rt][ct][r] / dnm[row];
                outp[(size_t)(rowblk + row) * RD + (wv * 32 + ct * 16 + l15)] =
                    fmaxf(v, 0.f);
            }
}

extern "C" void kernel_launch(void* const* d_in, const int* in_sizes, int n_in,
                              void* d_out, int out_size, void* d_ws, size_t ws_size,
                              hipStream_t stream)
{
    const float* relation = (const float*)d_in[0];
    const float* context  = (const float*)d_in[1];
    const float* adj      = (const float*)d_in[2];
    const float* W        = (const float*)d_in[3];
    const float* wl       = (const float*)d_in[4];
    const float* bl       = (const float*)d_in[5];
    const float* wr       = (const float*)d_in[6];
    const float* br       = (const float*)d_in[7];
    float* out = (float*)d_out;

    float* wsf   = (float*)d_ws;
    float* ul    = wsf;
    float* ur    = wsf + 512;
    float* left  = wsf + 1024;
    float* right = wsf + 1024 + 8192;
    const size_t hdr  = 81920;
    const size_t bf_b = (size_t)NREL * RD * 2;              // 4 MB fragments
    u32* Bf = (u32*)((char*)d_ws + hdr);

    if (ws_size >= hdr + bf_b) {
        hipLaunchKernelGGL(k_prep_bf, dim3(288), dim3(256), 0, stream,
                           W, wl, wr, ul, ur, relation, Bf);
        hipLaunchKernelGGL(k_lr, dim3(2048), dim3(256), 0, stream,
                           context, ul, ur, bl, br, left, right);
        hipLaunchKernelGGL(k_attn_seq, dim3(256), dim3(512), 0, stream,
                           adj, (const s16x8*)Bf, left, right, out);
    } else {
        hipLaunchKernelGGL(k_prep_bf, dim3(32), dim3(256), 0, stream,
                           W, wl, wr, ul, ur, relation, (u32*)nullptr);
        hipLaunchKernelGGL(k_lr, dim3(2048), dim3(256), 0, stream,
                           context, ul, ur, bl, br, left, right);
        hipLaunchKernelGGL(k_attn_leg, dim3(128), dim3(512), 0, stream,
                           adj, relation, left, right, out);
    }
}

// Round 20
// 102.511 us; speedup vs baseline: 1.1969x; 1.1969x over previous
//
#include <hip/hip_runtime.h>

#define NREL 8192
#define RD   256
#define RSHIFT 16.0f   // constant softmax shift: >= max(right) with huge margin

typedef float f32x4 __attribute__((ext_vector_type(4)));
typedef short s16x8 __attribute__((ext_vector_type(8)));
typedef unsigned int  u32;
typedef unsigned short u16;
typedef unsigned long long u64;
typedef u32 u32x4 __attribute__((ext_vector_type(4)));

__device__ __forceinline__ u16 f2bf(float f) {
    u32 b = __float_as_uint(f);
    return (u16)((b + 0x7FFFu + ((b >> 16) & 1u)) >> 16);   // RNE
}
__device__ __forceinline__ u32 pk_bf16(float lo, float hi) {
    u32 r;
    asm("v_cvt_pk_bf16_f32 %0, %1, %2" : "=v"(r) : "v"(lo), "v"(hi));
    return r;   // low16 = bf16(lo), high16 = bf16(hi), RNE
}

// ---------------- K1: fused {u_left/u_right} + {Bf fragment repack} ---------
__global__ __launch_bounds__(256) void k_prep_bf(
    const float* __restrict__ W, const float* __restrict__ wl,
    const float* __restrict__ wr, float* __restrict__ ul,
    float* __restrict__ ur, const float* __restrict__ R,
    u32* __restrict__ Bf)
{
    __shared__ float sL[256], sR[256];
    const int t = threadIdx.x;
    if (blockIdx.x < 32) {
        const int d = blockIdx.x * 16 + (t & 15);
        float aL = 0.f, aR = 0.f;
        for (int h = (t >> 4); h < 256; h += 16) {
            float w = W[h * 512 + d];
            aL += w * wl[h];
            aR += w * wr[h];
        }
        sL[t] = aL; sR[t] = aR;
        __syncthreads();
        if (t < 16) {
            float xL = 0.f, xR = 0.f;
            for (int g = 0; g < 16; g++) { xL += sL[g * 16 + t]; xR += sR[g * 16 + t]; }
            ul[blockIdx.x * 16 + t] = xL;
            ur[blockIdx.x * 16 + t] = xR;
        }
        return;
    }
    if (!Bf) return;
    const int b     = blockIdx.x - 32;
    const int jt    = b >> 1;
    const int fbase = (b & 1) * 1024;
    #pragma unroll
    for (int rep = 0; rep < 4; rep++) {
        const int f    = fbase + rep * 256 + t;   // 0..2047
        const int kk   = f >> 10;
        const int cg   = (f >> 6) & 15;
        const int lane = f & 63;
        const int lq   = lane >> 4;
        const int l15  = lane & 15;
        const int j0   = (jt << 6) + kk * 32 + lq * 8;
        const int n    = cg * 16 + l15;
        const float* src = R + (size_t)j0 * RD + n;
        float v[8];
        #pragma unroll
        for (int e = 0; e < 8; e++) v[e] = src[(size_t)e * RD];
        u32x4 w;
        w.x = pk_bf16(v[0], v[1]);
        w.y = pk_bf16(v[2], v[3]);
        w.z = pk_bf16(v[4], v[5]);
        w.w = pk_bf16(v[6], v[7]);
        *(u32x4*)(Bf + ((size_t)jt * 2048 + f) * 4) = w;
    }
}

// ---------------- K2: left/right rows (no atomics) --------------------------
__global__ __launch_bounds__(256) void k_lr(
    const float* __restrict__ ctx, const float* __restrict__ ul,
    const float* __restrict__ ur, const float* __restrict__ bl,
    const float* __restrict__ br, float* __restrict__ left,
    float* __restrict__ right)
{
    const int lane = threadIdx.x & 63;
    const int row  = blockIdx.x * 4 + (threadIdx.x >> 6);
    const f32x4* cv = (const f32x4*)(ctx + (size_t)row * 512);
    const f32x4* uv = (const f32x4*)ul;
    const f32x4* vv = (const f32x4*)ur;
    f32x4 c0 = cv[lane], c1 = cv[lane + 64];
    f32x4 u0 = uv[lane], u1 = uv[lane + 64];
    f32x4 v0 = vv[lane], v1 = vv[lane + 64];
    float dl = c0.x*u0.x + c0.y*u0.y + c0.z*u0.z + c0.w*u0.w
             + c1.x*u1.x + c1.y*u1.y + c1.z*u1.z + c1.w*u1.w;
    float dr = c0.x*v0.x + c0.y*v0.y + c0.z*v0.z + c0.w*v0.w
             + c1.x*v1.x + c1.y*v1.y + c1.z*v1.z + c1.w*v1.w;
    #pragma unroll
    for (int o = 1; o < 64; o <<= 1) { dl += __shfl_xor(dl, o); dr += __shfl_xor(dr, o); }
    if (lane == 0) {
        left[row]  = dl + bl[0];
        right[row] = dr + br[0];
    }
}

// ---------------- K3f: FUSED masked-softmax attention -----------------------
// 128-row blocks, 1024 thr (16 waves), K-split S; 2-deep adj prefetch.
// TILE-ORDER ROTATION: jt(i) = jt0 + ((i + rot) & (NT-1)), rot = bid & (NT-1).
// (round-16 structure: session best, 103.4 us)
template<int S>
__global__ __launch_bounds__(1024) void k_attn_f(
    const float* __restrict__ adj, const s16x8* __restrict__ Bf,
    const float* __restrict__ left, const float* __restrict__ right,
    float* __restrict__ pnum, float* __restrict__ pden)
{
    __shared__ u32 Pl[2][4096];     // 2 x 16 KB swizzled bf16 128x64 tiles
    constexpr int NT = 128 / S;     // tiles per split (32 at S=4)

    const int tid  = threadIdx.x;
    const int lane = tid & 63;
    const int wv   = tid >> 6;          // 0..15
    const int l15  = lane & 15;
    const int lq   = lane >> 4;
    const int rg   = wv >> 3;           // row half
    const int cg8  = wv & 7;            // col octant
    const int s      = (int)(blockIdx.x % (unsigned)S);
    const int rowblk = (int)(blockIdx.x / (unsigned)S) * 128;
    const int jt0 = s * NT;
    const int rot = (int)(blockIdx.x & (NT - 1));

    const int pr = tid >> 4;        // 0..63
    const int pq = tid & 15;

    const float lft0 = left[rowblk + pr];
    const float lft1 = left[rowblk + pr + 64];
    float z;
    z = lft0 + RSHIFT; const float m0 = fmaxf(z, 0.2f * z);
    z = lft1 + RSHIFT; const float m1 = fmaxf(z, 0.2f * z);

    f32x4 acc[4][2];
    #pragma unroll
    for (int i = 0; i < 4; i++) { acc[i][0] = (f32x4)0.f; acc[i][1] = (f32x4)0.f; }
    float dp0 = 0.f, dp1 = 0.f;

    const f32x4* adjv = (const f32x4*)adj;
    const f32x4* rv4  = (const f32x4*)right;
    const size_t arow0 = (size_t)(rowblk + pr) * 2048;
    const size_t arow1 = (size_t)(rowblk + pr + 64) * 2048;

    const u32 widx0 = (u32)pr * 32 + (((u32)pq * 2) ^ (((u32)pr & 7) << 2));
    const u32 widx1 = widx0 + 2048;

    #define JTOF(i) (jt0 + (((i) + rot) & (NT - 1)))

    f32x4 aA0 = adjv[arow0 + JTOF(0) * 16 + pq];
    f32x4 aA1 = adjv[arow1 + JTOF(0) * 16 + pq];
    f32x4 rvA = rv4[JTOF(0) * 16 + pq];
    f32x4 aB0 = adjv[arow0 + JTOF(1) * 16 + pq];
    f32x4 aB1 = adjv[arow1 + JTOF(1) * 16 + pq];
    f32x4 rvB = rv4[JTOF(1) * 16 + pq];
    s16x8 bA[2][2], bB[2][2];
    #pragma unroll
    for (int kk = 0; kk < 2; kk++)
        #pragma unroll
        for (int ct = 0; ct < 2; ct++)
            bA[kk][ct] = Bf[(size_t)JTOF(0) * 2048 + kk * 1024 + (cg8 * 2 + ct) * 64 + lane];

    for (int i = 0; i < NT; i += 2) {
        // ================= sub-iter 0: tile T(i) (slot A, Pl[0]) ============
        {
            float pa[4], pb[4];
            #pragma unroll
            for (int e = 0; e < 4; e++) {
                const float r = rvA[e];
                float z0 = lft0 + r; float s0 = fmaxf(z0, 0.2f * z0);
                pa[e] = aA0[e] * __expf(s0 - m0);
                float z1 = lft1 + r; float s1 = fmaxf(z1, 0.2f * z1);
                pb[e] = aA1[e] * __expf(s1 - m1);
            }
            dp0 += pa[0] + pa[1] + pa[2] + pa[3];
            dp1 += pb[0] + pb[1] + pb[2] + pb[3];
            Pl[0][widx0]     = pk_bf16(pa[0], pa[1]);
            Pl[0][widx0 + 1] = pk_bf16(pa[2], pa[3]);
            Pl[0][widx1]     = pk_bf16(pb[0], pb[1]);
            Pl[0][widx1 + 1] = pk_bf16(pb[2], pb[3]);

            asm volatile("s_waitcnt lgkmcnt(0)" ::: "memory");
            __builtin_amdgcn_s_barrier();

            const int j2 = JTOF((i + 2 < NT) ? i + 2 : 0);
            aA0 = adjv[arow0 + j2 * 16 + pq];
            aA1 = adjv[arow1 + j2 * 16 + pq];
            rvA = rv4[j2 * 16 + pq];
            const int jb1 = JTOF(i + 1);
            #pragma unroll
            for (int kk = 0; kk < 2; kk++)
                #pragma unroll
                for (int ct = 0; ct < 2; ct++)
                    bB[kk][ct] = Bf[(size_t)jb1 * 2048 + kk * 1024
                                    + (cg8 * 2 + ct) * 64 + lane];

            const u16* Pu = (const u16*)Pl[0];
            #pragma unroll
            for (int kk = 0; kk < 2; kk++) {
                s16x8 af[4];
                #pragma unroll
                for (int rt = 0; rt < 4; rt++) {
                    const int row = rg * 64 + rt * 16 + l15;
                    const int us  = row * 64 + ((kk * 32 + lq * 8) ^ ((row & 7) << 3));
                    af[rt] = *(const s16x8*)(Pu + us);
                }
                #pragma unroll
                for (int ct = 0; ct < 2; ct++)
                    #pragma unroll
                    for (int rt = 0; rt < 4; rt++)
                        acc[rt][ct] = __builtin_amdgcn_mfma_f32_16x16x32_bf16(
                            af[rt], bA[kk][ct], acc[rt][ct], 0, 0, 0);
            }
        }
        // ================= sub-iter 1: tile T(i+1) (slot B, Pl[1]) ==========
        {
            float pa[4], pb[4];
            #pragma unroll
            for (int e = 0; e < 4; e++) {
                const float r = rvB[e];
                float z0 = lft0 + r; float s0 = fmaxf(z0, 0.2f * z0);
                pa[e] = aB0[e] * __expf(s0 - m0);
                float z1 = lft1 + r; float s1 = fmaxf(z1, 0.2f * z1);
                pb[e] = aB1[e] * __expf(s1 - m1);
            }
            dp0 += pa[0] + pa[1] + pa[2] + pa[3];
            dp1 += pb[0] + pb[1] + pb[2] + pb[3];
            Pl[1][widx0]     = pk_bf16(pa[0], pa[1]);
            Pl[1][widx0 + 1] = pk_bf16(pa[2], pa[3]);
            Pl[1][widx1]     = pk_bf16(pb[0], pb[1]);
            Pl[1][widx1 + 1] = pk_bf16(pb[2], pb[3]);

            asm volatile("s_waitcnt lgkmcnt(0)" ::: "memory");
            __builtin_amdgcn_s_barrier();

            const int j3 = JTOF((i + 3 < NT) ? i + 3 : 0);
            aB0 = adjv[arow0 + j3 * 16 + pq];
            aB1 = adjv[arow1 + j3 * 16 + pq];
            rvB = rv4[j3 * 16 + pq];
            const int j2 = JTOF((i + 2 < NT) ? i + 2 : 0);
            #pragma unroll
            for (int kk = 0; kk < 2; kk++)
                #pragma unroll
                for (int ct = 0; ct < 2; ct++)
                    bA[kk][ct] = Bf[(size_t)j2 * 2048 + kk * 1024
                                    + (cg8 * 2 + ct) * 64 + lane];

            const u16* Pu = (const u16*)Pl[1];
            #pragma unroll
            for (int kk = 0; kk < 2; kk++) {
                s16x8 af[4];
                #pragma unroll
                for (int rt = 0; rt < 4; rt++) {
                    const int row = rg * 64 + rt * 16 + l15;
                    const int us  = row * 64 + ((kk * 32 + lq * 8) ^ ((row & 7) << 3));
                    af[rt] = *(const s16x8*)(Pu + us);
                }
                #pragma unroll
                for (int ct = 0; ct < 2; ct++)
                    #pragma unroll
                    for (int rt = 0; rt < 4; rt++)
                        acc[rt][ct] = __builtin_amdgcn_mfma_f32_16x16x32_bf16(
                            af[rt], bB[kk][ct], acc[rt][ct], 0, 0, 0);
            }
        }
    }
    #undef JTOF

    #pragma unroll
    for (int o = 1; o < 16; o <<= 1) { dp0 += __shfl_xor(dp0, o); dp1 += __shfl_xor(dp1, o); }
    if (pq == 0) {
        pden[(size_t)s * NREL + rowblk + pr]      = dp0;
        pden[(size_t)s * NREL + rowblk + pr + 64] = dp1;
    }
    float* pn = pnum + (size_t)s * NREL * RD;
    #pragma unroll
    for (int rt = 0; rt < 4; rt++)
        #pragma unroll
        for (int ct = 0; ct < 2; ct++)
            #pragma unroll
            for (int r = 0; r < 4; r++) {
                const int row = rg * 64 + rt * 16 + lq * 4 + r;
                pn[(size_t)(rowblk + row) * RD + (cg8 * 32 + ct * 16 + l15)] =
                    acc[rt][ct][r];
            }
}

// ---------------- K4: reduce partials: out = relu(sum num / sum den) --------
template<int S>
__global__ __launch_bounds__(256) void k_red(
    const float* __restrict__ pnum, const float* __restrict__ pden,
    float* __restrict__ out)
{
    const int idx = blockIdx.x * 256 + threadIdx.x;   // f32x4 index
    const int row = idx >> 6;
    float den = 0.f;
    #pragma unroll
    for (int s = 0; s < S; s++) den += pden[(size_t)s * NREL + row];
    const f32x4* pn4 = (const f32x4*)pnum;
    f32x4 a = (f32x4)0.f;
    #pragma unroll
    for (int s = 0; s < S; s++) a += pn4[(size_t)s * (NREL * RD / 4) + idx];
    f32x4 r;
    r.x = fmaxf(a.x / den, 0.f);
    r.y = fmaxf(a.y / den, 0.f);
    r.z = fmaxf(a.z / den, 0.f);
    r.w = fmaxf(a.w / den, 0.f);
    ((f32x4*)out)[idx] = r;
}

// ---------------- legacy fallback (tiny ws): direct adj, no precompute ------
__global__ __launch_bounds__(512) void k_attn_leg(
    const float* __restrict__ adj, const float* __restrict__ rel,
    const float* __restrict__ left, const float* __restrict__ right,
    float* __restrict__ outp)
{
    __shared__ u32   Pl[64 * 32];
    __shared__ float dnm[64];
    const int tid  = threadIdx.x;
    const int lane = tid & 63;
    const int wv   = tid >> 6;
    const int l15  = lane & 15;
    const int lq   = lane >> 4;
    const int rowblk = blockIdx.x * 64;
    const int pr = tid >> 4, pq = tid & 15;
    const float lft0 = left[rowblk + pr];
    const float lft1 = left[rowblk + pr + 32];
    float z;
    z = lft0 + RSHIFT; const float m0 = fmaxf(z, 0.2f * z);
    z = lft1 + RSHIFT; const float m1 = fmaxf(z, 0.2f * z);
    f32x4 acc[4][2];
    #pragma unroll
    for (int i = 0; i < 4; i++) { acc[i][0] = (f32x4)0.f; acc[i][1] = (f32x4)0.f; }
    float dp0 = 0.f, dp1 = 0.f;
    const f32x4* adjv = (const f32x4*)adj;
    const f32x4* rv4  = (const f32x4*)right;
    const size_t arow0 = (size_t)(rowblk + pr) * 2048;
    const size_t arow1 = (size_t)(rowblk + pr + 32) * 2048;
    const int n0 = wv * 32 + l15;
    const u32 widx0 = (u32)pr * 32 + (((u32)pq * 2) ^ (((u32)pr & 7) << 2));
    const u32 widx1 = widx0 + 1024;
    for (int jb = 0; jb < NREL; jb += 64) {
        f32x4 a0 = adjv[arow0 + (jb >> 2) + pq];
        f32x4 a1 = adjv[arow1 + (jb >> 2) + pq];
        f32x4 rv = rv4[(jb >> 2) + pq];
        s16x8 bc[2][2];
        #pragma unroll
        for (int kk = 0; kk < 2; kk++)
            #pragma unroll
            for (int ct = 0; ct < 2; ct++) {
                const float* rp = rel + (size_t)(jb + kk * 32 + lq * 8) * RD
                                      + (n0 + ct * 16);
                s16x8 b;
                #pragma unroll
                for (int e = 0; e < 8; e++) b[e] = (short)f2bf(rp[(size_t)e * RD]);
                bc[kk][ct] = b;
            }
        float pa[4], pb[4];
        #pragma unroll
        for (int e = 0; e < 4; e++) {
            const float r = rv[e];
            float z0 = lft0 + r; float s0 = fmaxf(z0, 0.2f * z0);
            pa[e] = a0[e] * __expf(s0 - m0);
            float z1 = lft1 + r; float s1 = fmaxf(z1, 0.2f * z1);
            pb[e] = a1[e] * __expf(s1 - m1);
        }
        dp0 += pa[0] + pa[1] + pa[2] + pa[3];
        dp1 += pb[0] + pb[1] + pb[2] + pb[3];
        Pl[widx0]     = pk_bf16(pa[0], pa[1]);
        Pl[widx0 + 1] = pk_bf16(pa[2], pa[3]);
        Pl[widx1]     = pk_bf16(pb[0], pb[1]);
        Pl[widx1 + 1] = pk_bf16(pb[2], pb[3]);
        __syncthreads();
        #pragma unroll
        for (int kk = 0; kk < 2; kk++) {
            s16x8 af[4];
            #pragma unroll
            for (int rt = 0; rt < 4; rt++) {
                const int row = rt * 16 + l15;
                const int us  = row * 64 + ((kk * 32 + lq * 8) ^ ((row & 7) << 3));
                af[rt] = *(const s16x8*)((const u16*)Pl + us);
            }
            #pragma unroll
            for (int ct = 0; ct < 2; ct++)
                #pragma unroll
                for (int rt = 0; rt < 4; rt++)
                    acc[rt][ct] = __builtin_amdgcn_mfma_f32_16x16x32_bf16(
                        af[rt], bc[kk][ct], acc[rt][ct], 0, 0, 0);
        }
        __syncthreads();
    }
    #pragma unroll
    for (int o = 1; o < 16; o <<= 1) { dp0 += __shfl_xor(dp0, o); dp1 += __shfl_xor(dp1, o); }
    if (pq == 0) { dnm[pr] = dp0; dnm[pr + 32] = dp1; }
    __syncthreads();
    #pragma unroll
    for (int rt = 0; rt < 4; rt++)
        #pragma unroll
        for (int ct = 0; ct < 2; ct++)
            #pragma unroll
            for (int r = 0; r < 4; r++) {
                const int row = rt * 16 + lq * 4 + r;
                float v = acc[rt][ct][r] / dnm[row];
                outp[(size_t)(rowblk + row) * RD + (wv * 32 + ct * 16 + l15)] =
                    fmaxf(v, 0.f);
            }
}

extern "C" void kernel_launch(void* const* d_in, const int* in_sizes, int n_in,
                              void* d_out, int out_size, void* d_ws, size_t ws_size,
                              hipStream_t stream)
{
    const float* relation = (const float*)d_in[0];
    const float* context  = (const float*)d_in[1];
    const float* adj      = (const float*)d_in[2];
    const float* W        = (const float*)d_in[3];
    const float* wl       = (const float*)d_in[4];
    const float* bl       = (const float*)d_in[5];
    const float* wr       = (const float*)d_in[6];
    const float* br       = (const float*)d_in[7];
    float* out = (float*)d_out;

    float* wsf   = (float*)d_ws;
    float* ul    = wsf;
    float* ur    = wsf + 512;
    float* left  = wsf + 1024;
    float* right = wsf + 1024 + 8192;
    const size_t hdr  = 81920;
    const size_t bf_b = (size_t)NREL * RD * 2;              // 4 MB fragments
    u32* Bf   = (u32*)((char*)d_ws + hdr);
    float* pnum = (float*)((char*)d_ws + hdr + bf_b);

    const int S = 4;
    const size_t need = hdr + bf_b
                      + (size_t)S * NREL * RD * 4 + (size_t)S * NREL * 4;

    if (ws_size >= need) {
        float* pden = pnum + (size_t)S * NREL * RD;
        hipLaunchKernelGGL(k_prep_bf, dim3(288), dim3(256), 0, stream,
                           W, wl, wr, ul, ur, relation, Bf);
        hipLaunchKernelGGL(k_lr, dim3(2048), dim3(256), 0, stream,
                           context, ul, ur, bl, br, left, right);
        hipLaunchKernelGGL((k_attn_f<4>), dim3(64 * 4), dim3(1024), 0, stream,
                           adj, (const s16x8*)Bf, left, right, pnum, pden);
        hipLaunchKernelGGL((k_red<4>), dim3(2048), dim3(256), 0, stream,
                           pnum, pden, out);
    } else {
        hipLaunchKernelGGL(k_prep_bf, dim3(32), dim3(256), 0, stream,
                           W, wl, wr, ul, ur, relation, (u32*)nullptr);
        hipLaunchKernelGGL(k_lr, dim3(2048), dim3(256), 0, stream,
                           context, ul, ur, bl, br, left, right);
        hipLaunchKernelGGL(k_attn_leg, dim3(128), dim3(512), 0, stream,
                           adj, relation, left, right, out);
    }
}